// Round 1
// 533.651 us; speedup vs baseline: 1.1056x; 1.1056x over previous
//
#include <hip/hip_runtime.h>
#include <hip/hip_bf16.h>

// Problem dims (compile-time constants)
#define NB   64
#define NH   64
#define NW   64
#define NCI  128
#define NCO  256
#define NHO  62
#define NWO  62
#define MTOT (NHO*NWO)   // 3844
#define KTOT (9*NCI)     // 1152

// GEMM tile config: 256x256 tile, 8 waves (2M x 4N), BK=64, LDS double-buffer,
// counted-vmcnt 4-phase K-loop (T3+T4), source-pre-swizzled LDS (T2),
// setprio around MFMA clusters (T5), XCD-chunked block swizzle (T1).
#define BM  256
#define BN  256
#define BK  64
#define NKT (KTOT/BK)    // 18 K-tiles -> 9 tile-pairs
#define MT  16           // ceil(3844/256) m-tiles per sample

using bf16x8 = __attribute__((ext_vector_type(8))) short;   // 8 bf16 = 4 VGPRs
using f32x4  = __attribute__((ext_vector_type(4))) float;

// async global->LDS, 16 B/lane; LDS dest = wave-uniform base + lane*16
__device__ __forceinline__ void gload_lds16(const __hip_bfloat16* g,
                                            __hip_bfloat16* l) {
    __builtin_amdgcn_global_load_lds(
        (const __attribute__((address_space(1))) unsigned int*)g,
        (__attribute__((address_space(3))) unsigned int*)l,
        16, 0, 0);
}

#define SBAR()   __builtin_amdgcn_s_barrier()
#define SCHED()  __builtin_amdgcn_sched_barrier(0)
#define VMCNT(n) asm volatile("s_waitcnt vmcnt(" #n ")" ::: "memory")

// ---------------------------------------------------------------------------
// Pass 1: X fp32 -> bf16 (64 MiB into ws). 8 elems/thread, 16B stores.
__global__ __launch_bounds__(256)
void cvt_x_kernel(const float* __restrict__ X,
                  __hip_bfloat16* __restrict__ Xb, int n8) {
    int i = blockIdx.x * 256 + threadIdx.x;
    if (i >= n8) return;
    const float4* p = (const float4*)X + (size_t)i * 2;
    float4 a = p[0], c = p[1];
    union { __hip_bfloat16 h[8]; float4 v; } u;
    u.h[0] = __float2bfloat16(a.x); u.h[1] = __float2bfloat16(a.y);
    u.h[2] = __float2bfloat16(a.z); u.h[3] = __float2bfloat16(a.w);
    u.h[4] = __float2bfloat16(c.x); u.h[5] = __float2bfloat16(c.y);
    u.h[6] = __float2bfloat16(c.z); u.h[7] = __float2bfloat16(c.w);
    *((float4*)Xb + i) = u.v;
}

// ---------------------------------------------------------------------------
// Pass 2: memWt[b][n][k] = bf16(W[k][n] * Werr[b][k][n])  (LDS-tiled transpose)
#define TK 64
#define TN 64
#define TPAD 65
__global__ __launch_bounds__(256)
void build_wt_kernel(const float* __restrict__ W,
                     const float* __restrict__ Werr,
                     __hip_bfloat16* __restrict__ Wt) {
    __shared__ __hip_bfloat16 tile[TK * TPAD];
    const int t  = threadIdx.x;
    const int b  = blockIdx.z;
    const int k0 = blockIdx.x * TK;
    const int n0 = blockIdx.y * TN;

    const int c4 = (t & 15) * 4;   // n offset within tile
    const int r  = t >> 4;         // k row within 16-row pass
    const float* wb = W + n0;
    const float* eb = Werr + (size_t)b * (KTOT * NCO) + n0;
#pragma unroll
    for (int p = 0; p < 4; p++) {
        int k  = k0 + r + p * 16;
        int kl = r + p * 16;
        float4 w = *(const float4*)(wb + (size_t)k * NCO + c4);
        float4 e = *(const float4*)(eb + (size_t)k * NCO + c4);
        tile[kl * TPAD + c4 + 0] = __float2bfloat16(w.x * e.x);
        tile[kl * TPAD + c4 + 1] = __float2bfloat16(w.y * e.y);
        tile[kl * TPAD + c4 + 2] = __float2bfloat16(w.z * e.z);
        tile[kl * TPAD + c4 + 3] = __float2bfloat16(w.w * e.w);
    }
    __syncthreads();
    const int np = t >> 2;
    const int ks = (t & 3) * 16;
    __hip_bfloat16* ob = Wt + ((size_t)b * NCO + n0 + np) * KTOT + k0 + ks;
    union { __hip_bfloat16 h[8]; float4 v; } u;
#pragma unroll
    for (int h2 = 0; h2 < 2; h2++) {
#pragma unroll
        for (int q = 0; q < 8; q++) u.h[q] = tile[(ks + h2 * 8 + q) * TPAD + np];
        *(float4*)(ob + h2 * 8) = u.v;
    }
}

// ---------------------------------------------------------------------------
// Pass 3: per-sample implicit GEMM, bf16 MFMA 16x16x32.
// C[m,n] = sum_k A[m,k]*Wt[n,k];  m=(oh,ow) spatial, k=(kh,kw,ci).
// One block = one (sample, m-tile): 256x256 output, 512 threads / 8 waves.
// LDS per K-tile: A 256x64 bf16 (32 KiB) + B 256x64 (32 KiB), double-buffered.
//
// Staging map: thread T, chunk l=0..3: row = l*64 + T/8, lds 16B-slot = T%8.
// Global source slot is pre-swizzled: gslot = slot ^ (row&7) so that reads can
// use the XOR-swizzled offset (linear global_load_lds dest, rule both-sides).
//
// K-loop schedule per iteration (tiles 2s in buf0, 2s+1 in buf1):
//   PHASE(0,k0) PHASE(0,k1) | BAR | STAGE(0, 2s+2) | vmcnt(8) BAR |
//   PHASE(1,k0) PHASE(1,k1) | BAR | STAGE(1, 2s+3) | vmcnt(8) BAR
// Invariant: at each vmcnt(8) the <=8 surviving loads are exactly the newest
// (not-yet-consumed) tile's; everything older (the tile about to be read by
// all waves after the barrier) has retired. vmcnt never drains to 0 except in
// the peeled final tile-pair.
__global__ __launch_bounds__(512, 2)
void gemm_bf16_kernel(const __hip_bfloat16* __restrict__ Xb,
                      const __hip_bfloat16* __restrict__ Wt,
                      const float* __restrict__ bias,
                      const float* __restrict__ Berr,
                      float* __restrict__ out) {
    __shared__ __hip_bfloat16 lds[2][2][BM * BK];   // [buf][A=0/B=1], 128 KiB

    const int t    = threadIdx.x;
    const int lane = t & 63;
    const int wave = t >> 6;

    // T1: bijective XCD chunking (nwg = 1024, 1024 % 8 == 0).
    // XCD x gets logical chunk [x*128, x*128+128) = 8 whole samples.
    const int bid = blockIdx.x;
    const int swz = (bid & 7) * ((NB * MT) / 8) + (bid >> 3);
    const int b   = swz >> 4;          // sample (16 m-tiles each)
    const int m0  = (swz & 15) * BM;   // m-tile origin

    const __hip_bfloat16* xbase = Xb + (size_t)b * (NH * NW * NCI);
    const __hip_bfloat16* wbase = Wt + (size_t)b * NCO * KTOT;

    // ---- staging geometry -------------------------------------------------
    const int srow  = t >> 3;                 // row within 64-row chunk
    const int gslot = (t & 7) ^ (srow & 7);   // inverse-swizzled source slot

    int aoffg[4], boffg[4];
#pragma unroll
    for (int l = 0; l < 4; l++) {
        int row = l * 64 + srow;
        int m = m0 + row; if (m > MTOT - 1) m = MTOT - 1;   // clamp edge rows
        int oh = m / NWO, ow = m - oh * NWO;
        aoffg[l] = (oh * NW + ow) * NCI + gslot * 8;
        boffg[l] = row * KTOT + gslot * 8;
    }

    auto STAGE = [&](int buf, int kt) {
        const int k0 = kt * BK;
        const int kh = k0 / (3 * NCI);          // BK=64 divides NCI -> one (kh,kw)
        const int rm = k0 - kh * (3 * NCI);
        const int kw = rm / NCI;
        const int ci = rm - kw * NCI;
        const int kuA = (kh * NW + kw) * NCI + ci;
        __hip_bfloat16* lA = &lds[buf][0][wave * 512];   // wave-uniform bases
        __hip_bfloat16* lB = &lds[buf][1][wave * 512];
#pragma unroll
        for (int l = 0; l < 4; l++) {
            gload_lds16(xbase + aoffg[l] + kuA, lA + l * 4096);
            gload_lds16(wbase + boffg[l] + k0,  lB + l * 4096);
        }
    };

    // ---- fragment geometry ------------------------------------------------
    const int lrow = lane & 15, quad = lane >> 4;
    const int wm = wave >> 2;          // 0..1 -> m-half (128 rows)
    const int wn = wave & 3;           // 0..3 -> n-quarter (64 cols)
    const int fswz = (lrow & 7) << 3;  // read-side XOR (elements)

    f32x4 acc[8][4];
#pragma unroll
    for (int i = 0; i < 8; i++)
#pragma unroll
        for (int j = 0; j < 4; j++) acc[i][j] = (f32x4){0.f, 0.f, 0.f, 0.f};

    auto PHASE = [&](int buf, int kk) {   // one k-half (32) of one K-tile
        const __hip_bfloat16* A  = &lds[buf][0][0];
        const __hip_bfloat16* Bp = &lds[buf][1][0];
        const int ks = (kk * 32 + quad * 8) ^ fswz;
        bf16x8 af[8], bf[4];
#pragma unroll
        for (int i = 0; i < 8; i++)
            af[i] = *(const bf16x8*)&A[(wm * 128 + i * 16 + lrow) * BK + ks];
#pragma unroll
        for (int j = 0; j < 4; j++)
            bf[j] = *(const bf16x8*)&Bp[(wn * 64 + j * 16 + lrow) * BK + ks];
        __builtin_amdgcn_s_setprio(1);
#pragma unroll
        for (int i = 0; i < 8; i++)
#pragma unroll
            for (int j = 0; j < 4; j++)
                acc[i][j] = __builtin_amdgcn_mfma_f32_16x16x32_bf16(
                    af[i], bf[j], acc[i][j], 0, 0, 0);
        __builtin_amdgcn_s_setprio(0);
    };

    // ---- prologue ----------------------------------------------------------
    STAGE(0, 0);
    STAGE(1, 1);
    VMCNT(8); SCHED();     // tile 0 landed (wave-local)
    SBAR(); SCHED();       // ... and in every wave

    // ---- main loop: 8 iterations, tiles 0..15 ------------------------------
    for (int s = 0; s < NKT / 2 - 1; ++s) {
        PHASE(0, 0); PHASE(0, 1);
        SCHED(); SBAR(); SCHED();       // all waves done reading buf0
        STAGE(0, 2 * s + 2);
        VMCNT(8); SCHED();              // tile 2s+1 retired (newest 8 = 2s+2)
        SBAR(); SCHED();
        PHASE(1, 0); PHASE(1, 1);
        SCHED(); SBAR(); SCHED();       // all waves done reading buf1
        STAGE(1, 2 * s + 3);
        VMCNT(8); SCHED();              // tile 2s+2 retired (newest 8 = 2s+3)
        SBAR(); SCHED();
    }
    // ---- peeled last pair: tiles 16 (buf0), 17 (buf1) ----------------------
    PHASE(0, 0); PHASE(0, 1);
    VMCNT(0); SCHED();                  // only drain-to-0 in the kernel
    SBAR(); SCHED();
    PHASE(1, 0); PHASE(1, 1);

    // ---- epilogue: + bias[n]*Berr[b][n]; C/D: col=lrow, row=quad*4+reg -----
    float bv[4];
#pragma unroll
    for (int j = 0; j < 4; j++) {
        int n = wn * 64 + j * 16 + lrow;
        bv[j] = bias[n] * Berr[b * NCO + n];
    }
#pragma unroll
    for (int i = 0; i < 8; i++) {
#pragma unroll
        for (int r = 0; r < 4; r++) {
            int m = m0 + wm * 128 + i * 16 + quad * 4 + r;
            if (m < MTOT) {
                float* op = out + ((size_t)b * MTOT + m) * NCO;
#pragma unroll
                for (int j = 0; j < 4; j++)
                    op[wn * 64 + j * 16 + lrow] = acc[i][j][r] + bv[j];
            }
        }
    }
}

// ---------------------------------------------------------------------------
// Safety net if ws is too small for the bf16 staging (~100 MiB): naive direct
// conv, correct but slow. Should never trigger on the real harness.
__global__ void naive_conv_kernel(const float* __restrict__ X,
                                  const float* __restrict__ W,
                                  const float* __restrict__ bias,
                                  const float* __restrict__ Werr,
                                  const float* __restrict__ Berr,
                                  float* __restrict__ out) {
    size_t idx = (size_t)blockIdx.x * 256 + threadIdx.x;
    if (idx >= (size_t)NB * MTOT * NCO) return;
    int n = idx % NCO;
    size_t m = idx / NCO;
    int ow = m % NWO; size_t t2 = m / NWO;
    int oh = t2 % NHO; int b = t2 / NHO;
    float acc = bias[n] * Berr[b * NCO + n];
    for (int kh = 0; kh < 3; kh++)
        for (int kw = 0; kw < 3; kw++) {
            const float* xp = X + (((size_t)b * NH + oh + kh) * NW + ow + kw) * NCI;
            const float* wp = W + ((kh * 3 + kw) * NCI) * (size_t)NCO + n;
            const float* ep = Werr + (size_t)b * KTOT * NCO + ((kh * 3 + kw) * NCI) * (size_t)NCO + n;
            for (int ci = 0; ci < NCI; ci++)
                acc += xp[ci] * wp[ci * NCO] * ep[ci * NCO];
        }
    out[idx] = acc;
}

// ---------------------------------------------------------------------------
extern "C" void kernel_launch(void* const* d_in, const int* in_sizes, int n_in,
                              void* d_out, int out_size, void* d_ws, size_t ws_size,
                              hipStream_t stream) {
    const float* X    = (const float*)d_in[0];
    const float* W    = (const float*)d_in[1];
    const float* bias = (const float*)d_in[2];
    const float* Werr = (const float*)d_in[3];
    const float* Berr = (const float*)d_in[4];
    float* out = (float*)d_out;

    const size_t xb_bytes = (size_t)NB * NH * NW * NCI * 2;   // 64 MiB
    const size_t wt_bytes = (size_t)NB * NCO * KTOT * 2;      // 36 MiB

    if (ws_size < xb_bytes + wt_bytes) {
        size_t total = (size_t)NB * MTOT * NCO;
        naive_conv_kernel<<<(int)((total + 255) / 256), 256, 0, stream>>>(
            X, W, bias, Werr, Berr, out);
        return;
    }

    __hip_bfloat16* Xb = (__hip_bfloat16*)d_ws;
    __hip_bfloat16* Wt = (__hip_bfloat16*)((char*)d_ws + xb_bytes);

    int n8 = NB * NH * NW * NCI / 8;                           // 4,194,304
    cvt_x_kernel<<<n8 / 256, 256, 0, stream>>>(X, Xb, n8);
    build_wt_kernel<<<dim3(KTOT / TK, NCO / TN, NB), 256, 0, stream>>>(W, Werr, Wt);
    gemm_bf16_kernel<<<dim3(NB * MT), 512, 0, stream>>>(
        Xb, Wt, bias, Berr, out);
}